// Round 1
// baseline (115.436 us; speedup 1.0000x reference)
//
#include <hip/hip_runtime.h>
#include <stdint.h>

#define N_ROWS 8192
#define DIM 128
#define LDA 136        // LDS pitch in bf16 elems: 128+8 -> 272B rows, 2-way bank alias (free)
#define BM 128
#define JCHUNK 1024
#define NJT (JCHUNK / BM)

typedef short bf16x8 __attribute__((ext_vector_type(8)));
typedef float f32x4 __attribute__((ext_vector_type(4)));

template <bool B> struct BoolC { static constexpr bool value = B; };

__device__ __forceinline__ unsigned int f2bf(float x) {
  union { float f; unsigned u; } c; c.f = x;
  return (c.u + 0x7FFFu + ((c.u >> 16) & 1u)) >> 16;  // RNE to bf16
}

// Kernel 1: L2-normalize rows fp32 -> bf16 (ws), zero Z/S/P accumulators.
__global__ __launch_bounds__(256) void normalize_kernel(
    const float* __restrict__ F, unsigned short* __restrict__ Abf,
    float* __restrict__ Z, float* __restrict__ S, float* __restrict__ P) {
  const int wave = threadIdx.x >> 6, lane = threadIdx.x & 63;
  const int row = blockIdx.x * 4 + wave;
  float2 v = ((const float2*)(F + (size_t)row * DIM))[lane];
  float ss = v.x * v.x + v.y * v.y;
  #pragma unroll
  for (int m = 1; m < 64; m <<= 1) ss += __shfl_xor(ss, m, 64);
  float scale = rsqrtf(fmaxf(ss, 1e-24f));
  unsigned bx = f2bf(v.x * scale), by = f2bf(v.y * scale);
  ((unsigned*)Abf)[(size_t)row * (DIM / 2) + lane] = bx | (by << 16);
  if (lane == 0) { Z[row] = 0.f; S[row] = 0.f; P[row] = 0.f; }
}

// Kernel 2: fused  C = A*A^T / T  ->  online {Z, S, P} accumulation.
// Block: 256 thr (4 waves, 2x2 of 64x64), I-tile 128 rows x J-chunk 1024 cols.
__global__ __launch_bounds__(256, 2) void scl_fused_kernel(
    const unsigned short* __restrict__ Abf, const int* __restrict__ L,
    float* __restrict__ Z, float* __restrict__ S, float* __restrict__ P) {
  __shared__ unsigned short sA[BM * LDA];
  __shared__ unsigned short sB[BM * LDA];

  const int tid = threadIdx.x;
  const int lane = tid & 63;
  const int wave = tid >> 6;
  const int wi = wave >> 1, wj = wave & 1;
  const int quad = lane >> 4, l15 = lane & 15;

  const int i0 = blockIdx.y * BM;
  const int j0 = blockIdx.x * JCHUNK;

  // stage A_I tile (128 x 128 bf16, 16B per thread-chunk)
  #pragma unroll
  for (int k = 0; k < 8; ++k) {
    int idx = tid + k * 256;           // 0..2047 ; row = idx/16, 16B col chunk = idx%16
    int r = idx >> 4, c = idx & 15;
    uint4 v = ((const uint4*)(Abf + (size_t)(i0 + r) * DIM))[c];
    *(uint4*)&sA[r * LDA + c * 8] = v;
  }

  // this lane's 16 row labels (ti x reg), fixed for the whole block
  int labI[16];
  #pragma unroll
  for (int ti = 0; ti < 4; ++ti)
    #pragma unroll
    for (int rg = 0; rg < 4; ++rg)
      labI[ti * 4 + rg] = L[i0 + wi * 64 + ti * 16 + quad * 4 + rg];

  float zacc[16], sacc[16], pacc[16];
  #pragma unroll
  for (int q = 0; q < 16; ++q) { zacc[q] = 0.f; sacc[q] = 0.f; pacc[q] = 0.f; }

  const float K1 = 20.6099291555566280f;  // log2(e)/0.07 ; t = c*K1 - K1 ; e = exp2(t)

  for (int jt = 0; jt < NJT; ++jt) {
    __syncthreads();                     // prior iter done reading sB
    const int jb = j0 + jt * BM;
    #pragma unroll
    for (int k = 0; k < 8; ++k) {
      int idx = tid + k * 256;
      int r = idx >> 4, c = idx & 15;
      uint4 v = ((const uint4*)(Abf + (size_t)(jb + r) * DIM))[c];
      *(uint4*)&sB[r * LDA + c * 8] = v;
    }
    __syncthreads();

    f32x4 acc[4][4];
    #pragma unroll
    for (int a = 0; a < 4; ++a)
      #pragma unroll
      for (int b = 0; b < 4; ++b)
        acc[a][b] = (f32x4){0.f, 0.f, 0.f, 0.f};

    #pragma unroll
    for (int ks = 0; ks < 4; ++ks) {
      bf16x8 af[4], bfr[4];
      #pragma unroll
      for (int ti = 0; ti < 4; ++ti)
        af[ti] = *(const bf16x8*)&sA[(wi * 64 + ti * 16 + l15) * LDA + ks * 32 + quad * 8];
      #pragma unroll
      for (int tj = 0; tj < 4; ++tj)
        bfr[tj] = *(const bf16x8*)&sB[(wj * 64 + tj * 16 + l15) * LDA + ks * 32 + quad * 8];
      #pragma unroll
      for (int ti = 0; ti < 4; ++ti)
        #pragma unroll
        for (int tj = 0; tj < 4; ++tj)
          acc[ti][tj] = __builtin_amdgcn_mfma_f32_16x16x32_bf16(af[ti], bfr[tj], acc[ti][tj], 0, 0, 0);
    }

    // this lane's 4 col labels for this J-tile
    int labJ[4];
    #pragma unroll
    for (int tj = 0; tj < 4; ++tj)
      labJ[tj] = L[jb + wj * 64 + tj * 16 + l15];

    // epilogue: C/D layout col = lane&15, row = quad*4 + reg
    auto epi = [&](auto DIAG) {
      #pragma unroll
      for (int ti = 0; ti < 4; ++ti) {
        #pragma unroll
        for (int rg = 0; rg < 4; ++rg) {
          const int li = labI[ti * 4 + rg];
          const int gi = i0 + wi * 64 + ti * 16 + quad * 4 + rg;
          float z = 0.f, s = 0.f, p = 0.f;
          #pragma unroll
          for (int tj = 0; tj < 4; ++tj) {
            float c = acc[ti][tj][rg];
            float t = fmaf(c, K1, -K1);
            float e = exp2f(t);
            bool sm = (li == labJ[tj]);
            if constexpr (decltype(DIAG)::value) {
              int gj = jb + wj * 64 + tj * 16 + l15;
              bool od = (gi != gj);
              e = od ? e : 0.f;
              sm = sm && od;
            }
            z += e;
            s += sm ? t : 0.f;
            p += sm ? 1.f : 0.f;
          }
          zacc[ti * 4 + rg] += z;
          sacc[ti * 4 + rg] += s;
          pacc[ti * 4 + rg] += p;
        }
      }
    };
    if (jb == i0) epi(BoolC<true>{}); else epi(BoolC<false>{});
  }

  // cross-lane reduce over the 16 columns lanes of each quad, then atomics
  #pragma unroll
  for (int q = 0; q < 16; ++q) {
    float z = zacc[q], s = sacc[q], p = pacc[q];
    #pragma unroll
    for (int m = 1; m < 16; m <<= 1) {
      z += __shfl_xor(z, m, 64);
      s += __shfl_xor(s, m, 64);
      p += __shfl_xor(p, m, 64);
    }
    if (l15 == 0) {
      int ti = q >> 2, rg = q & 3;
      int gi = i0 + wi * 64 + ti * 16 + quad * 4 + rg;
      atomicAdd(&Z[gi], z);
      atomicAdd(&S[gi], s);
      atomicAdd(&P[gi], p);
    }
  }
}

// Kernel 3: per-row loss + mean.  S is in exp2-units: logit-sum = S * ln2.
__global__ __launch_bounds__(256) void finalize_kernel(
    const float* __restrict__ Z, const float* __restrict__ S,
    const float* __restrict__ P, float* __restrict__ out) {
  __shared__ float red[4];
  const int tid = threadIdx.x, lane = tid & 63, wave = tid >> 6;
  float acc = 0.f;
  for (int r = tid; r < N_ROWS; r += 256) {
    float lp = (S[r] * 0.69314718055994531f) / P[r] - logf(Z[r] + 1e-12f);
    acc += lp;
  }
  #pragma unroll
  for (int m = 1; m < 64; m <<= 1) acc += __shfl_xor(acc, m, 64);
  if (lane == 0) red[wave] = acc;
  __syncthreads();
  if (tid == 0) out[0] = -(red[0] + red[1] + red[2] + red[3]) / (float)N_ROWS;
}

extern "C" void kernel_launch(void* const* d_in, const int* in_sizes, int n_in,
                              void* d_out, int out_size, void* d_ws, size_t ws_size,
                              hipStream_t stream) {
  const float* F = (const float*)d_in[0];
  const int* L = (const int*)d_in[1];
  unsigned short* Abf = (unsigned short*)d_ws;                       // 8192*128 bf16 = 2 MB
  float* Z = (float*)((char*)d_ws + (size_t)N_ROWS * DIM * 2);
  float* S = Z + N_ROWS;
  float* P = S + N_ROWS;
  float* out = (float*)d_out;

  normalize_kernel<<<N_ROWS / 4, 256, 0, stream>>>(F, Abf, Z, S, P);
  dim3 grid(N_ROWS / JCHUNK, N_ROWS / BM);  // (8, 64) = 512 blocks
  scl_fused_kernel<<<grid, 256, 0, stream>>>(Abf, L, Z, S, P);
  finalize_kernel<<<1, 256, 0, stream>>>(Z, S, P, out);
}